// Round 5
// baseline (229.477 us; speedup 1.0000x reference)
//
#include <hip/hip_runtime.h>

// ---------------------------------------------------------------------------
// Problem constants
//   B=16, C=512, H=W=32 -> T=1024, HEADS=8, HD=64, pairs F=32
// ---------------------------------------------------------------------------

typedef __bf16 bf16x8 __attribute__((ext_vector_type(8)));
typedef __bf16 bf16x4 __attribute__((ext_vector_type(4)));
typedef float  f32x4  __attribute__((ext_vector_type(4)));

__device__ __forceinline__ f32x4 mfma16(bf16x8 a, bf16x8 b, f32x4 c) {
    return __builtin_amdgcn_mfma_f32_16x16x32_bf16(a, b, c, 0, 0, 0);
}

// async 16B global -> LDS (dest = wave-uniform base + lane*16)
__device__ __forceinline__ void async16(const void* g, void* l) {
    __builtin_amdgcn_global_load_lds(
        (const __attribute__((address_space(1))) void*)g,
        (__attribute__((address_space(3))) void*)l, 16, 0, 0);
}

// ---------------------------------------------------------------------------
// 1) weight conversion fp32 -> bf16.
//    wo k-PERMUTED: wob[o][nh*64+hd] = wo[o][hd*8+nh] (head-major od2).
// ---------------------------------------------------------------------------
__global__ void k_convert_w(const float* __restrict__ wq, const float* __restrict__ wo,
                            __bf16* __restrict__ wqb, __bf16* __restrict__ wob) {
    int i = blockIdx.x * 256 + threadIdx.x;          // grid covers 786432
    if (i < 3 * 512 * 512) wqb[i] = (__bf16)wq[i];
    if (i < 512 * 512) {
        int o = i >> 9, k2 = i & 511;
        int nh = k2 >> 6, hd = k2 & 63;
        wob[i] = (__bf16)wo[o * 512 + hd * 8 + nh];
    }
}

// ---------------------------------------------------------------------------
// 2) x [B][C][T] fp32  ->  xt [B*T][C] bf16   (LDS tile transpose)
//    R(this): 64x64 tile, block (64,4): stores are full 128B lines (were
//    64B half-lines), loads 256B. tile[64][65]: both phases 2-way bank
//    alias only (free, m136). Grid (16,8,16) = 2048 blocks.
// ---------------------------------------------------------------------------
__global__ void k_transpose_x(const float* __restrict__ x, __bf16* __restrict__ xt) {
    __shared__ float tile[64][65];                   // 16.6 KB
    const int b  = blockIdx.z;
    const int c0 = blockIdx.y * 64;
    const int t0 = blockIdx.x * 64;
    const int tx = threadIdx.x, ty = threadIdx.y;    // (64, 4)
    const float* xp = x + ((size_t)b * 512 + c0) * 1024 + t0;
#pragma unroll
    for (int j = 0; j < 16; j++)
        tile[ty + j * 4][tx] = xp[(ty + j * 4) * 1024 + tx];
    __syncthreads();
    __bf16* xo = xt + ((size_t)b * 1024 + t0) * 512 + c0;
#pragma unroll
    for (int j = 0; j < 16; j++)
        xo[(ty + j * 4) * 512 + tx] = (__bf16)tile[tx][ty + j * 4];
}

// ---------------------------------------------------------------------------
// 3) QKV GEMM 16384x1536x512 + fused bias + SO(2) rotation + head split.
//    R(this): async DOUBLE-BUFFER. Old: 8 serial K-iters, each paying the
//    full HBM latency inside stage->drain->barrier->compute (latency-bound:
//    Mfma 14 / VALU 23 / HBM 15 / occ 20 all idle). New: stage(t+1) issued
//    BEFORE compute(t); the one __syncthreads per iter drains vmcnt AFTER
//    ~400cyc of MFMA has hidden the load. Halves barrier count too.
//    LDS 64 KB (2 blocks/CU). Grid 128x12, head-grouped columns (R1),
//    q pre-scaled by 0.125*log2e (R3).
// ---------------------------------------------------------------------------
__global__ __launch_bounds__(256) void k_gemm_qkv(
        const __bf16* __restrict__ A, const __bf16* __restrict__ W,
        const float* __restrict__ bias,
        const float* __restrict__ matq, const float* __restrict__ matk,
        const float* __restrict__ matv,
        __bf16* __restrict__ qd, __bf16* __restrict__ kd, __bf16* __restrict__ vtd)
{
    __shared__ __bf16 As[2][128][64];   // 32 KB
    __shared__ __bf16 Bs[2][128][64];   // 32 KB
    const int tid = threadIdx.x;
    const int m0 = blockIdx.x * 128;
    const int jb = blockIdx.y;              // 0..11
    const int part = jb >> 2;               // 0=q 1=k 2=v (uniform per block)
    const int nh_base = (jb & 3) * 2;       // heads {nh_base, nh_base+1}
    const int lane = tid & 63, w = tid >> 6;
    const int ln = lane & 15, quad = lane >> 4;
    const int wr = w >> 1, wc = w & 1;      // 2x2 wave grid, 64x64 each

    const int srow = lane >> 3;                       // 0..7
    const int scol = (((lane & 7) ^ srow) * 8);       // xor chunk swizzle

    const __bf16* arow[4];
    const __bf16* brow[4];
#pragma unroll
    for (int jj = 0; jj < 4; jj++) {
        int rr = w * 32 + jj * 8 + srow;              // 0..127
        arow[jj] = &A[(size_t)(m0 + rr) * 512 + scol];
        int o = part * 512 + (rr & 63) * 8 + nh_base + (rr >> 6);
        brow[jj] = &W[(size_t)o * 512 + scol];
    }

    f32x4 acc[4][4] = {};

    // prologue: stage k-tile 0 into buf 0
#pragma unroll
    for (int jj = 0; jj < 4; jj++) {
        async16(arow[jj], &As[0][w * 32 + jj * 8][0]);
        async16(brow[jj], &Bs[0][w * 32 + jj * 8][0]);
    }
    __syncthreads();

#pragma unroll
    for (int it = 0; it < 8; ++it) {
        const int cur = it & 1;
        if (it < 7) {                      // prefetch next k-tile into buf^1
            const int k1 = (it + 1) * 64;
#pragma unroll
            for (int jj = 0; jj < 4; jj++) {
                async16(arow[jj] + k1, &As[cur ^ 1][w * 32 + jj * 8][0]);
                async16(brow[jj] + k1, &Bs[cur ^ 1][w * 32 + jj * 8][0]);
            }
        }
#pragma unroll
        for (int h = 0; h < 2; h++) {
            bf16x8 af[4], wf[4];
#pragma unroll
            for (int mi = 0; mi < 4; mi++)
                af[mi] = *(const bf16x8*)&As[cur][wr * 64 + mi * 16 + ln][(((h * 4 + quad) ^ (ln & 7)) * 8)];
#pragma unroll
            for (int ni = 0; ni < 4; ni++)
                wf[ni] = *(const bf16x8*)&Bs[cur][wc * 64 + ni * 16 + ln][(((h * 4 + quad) ^ (ln & 7)) * 8)];
#pragma unroll
            for (int mi = 0; mi < 4; mi++)
#pragma unroll
                for (int ni = 0; ni < 4; ni++)
                    acc[mi][ni] = mfma16(af[mi], wf[ni], acc[mi][ni]);
        }
        __syncthreads();    // implicit vmcnt(0): prefetch landed under MFMA
    }

    const int nh = nh_base + wc;
    const int rowbase = m0 + wr * 64;
    const int b  = rowbase >> 10, t0 = rowbase & 1023;
    const int bh = b * 8 + nh;
    const int ip = ln & 1;
    const float2* matp = (const float2*)(part == 0 ? matq : (part == 1 ? matk : matv));
    __bf16* qkdst = (part == 0) ? qd : kd;
    // q gets the softmax scale folded in (pre-cast: single rounding)
    const float qscale = (part == 0) ? 0.18033688011112042f : 1.0f;

#pragma unroll
    for (int ni = 0; ni < 4; ni++) {
        const int hd = ni * 16 + ln;
        const int f  = hd >> 1;
        const float bias_o = bias[part * 512 + hd * 8 + nh];
#pragma unroll
        for (int mi = 0; mi < 4; mi++) {
            const int tq = t0 + mi * 16 + quad * 4;   // first of this frag's 4 t's
            if (part < 2) {
#pragma unroll
                for (int r = 0; r < 4; r++) {
                    int t = tq + r;
                    float val = acc[mi][ni][r] + bias_o;
                    float pr  = __shfl_xor(val, 1);
                    float2 mv = matp[((size_t)t * 32 + f) * 2 + ip];
                    float e  = ip ? pr : val;
                    float oo = ip ? val : pr;
                    float rv = (mv.x * e + mv.y * oo) * qscale;
                    qkdst[((size_t)bh * 1024 + t) * 64 + hd] = (__bf16)rv;
                }
            } else {
                __bf16 pack[4];
#pragma unroll
                for (int r = 0; r < 4; r++) {
                    int t = tq + r;
                    float val = acc[mi][ni][r] + bias_o;
                    float pr  = __shfl_xor(val, 1);
                    float2 mv = matp[((size_t)t * 32 + f) * 2 + ip];
                    float e  = ip ? pr : val;
                    float oo = ip ? val : pr;
                    pack[r] = (__bf16)(mv.x * e + mv.y * oo);
                }
                *(uint2*)&vtd[((size_t)bh * 64 + hd) * 1024 + tq] = *(const uint2*)pack;
            }
        }
    }
}

// ---------------------------------------------------------------------------
// 4) Flash attention. 512 threads / 8 waves, 16 q-rows per wave (R4:
//    occupancy 60%). Swapped QK^T, transposed PV, ones-MFMA l-sums,
//    head-major od2 stores, q pre-scaled. Unchanged this round.
// ---------------------------------------------------------------------------
__global__ __launch_bounds__(512) void k_attn(
        const __bf16* __restrict__ q, const __bf16* __restrict__ kk,
        const __bf16* __restrict__ vt, const float* __restrict__ mato,
        __bf16* __restrict__ od)
{
    __shared__ __bf16 Ks[64][64];        // [s][d]   8 KB, XOR-chunk layout
    __shared__ __bf16 Vs[64][64];        // [hd][s]  8 KB, XOR-chunk layout
    __shared__ __bf16 Ps[8][16][64];     // per-wave P (rows=q), 16 KB
    const int bh = blockIdx.x, qt = blockIdx.y;
    const int tid = threadIdx.x, w = tid >> 6, lane = tid & 63;
    const int ln = lane & 15, quad = lane >> 4;
    const int lx = ln & 7;                       // xor key for frag reads
    const int srow = lane >> 3;
    const int scol = ((lane & 7) ^ srow) * 8;    // xor chunk source swizzle
    const int qr0 = qt * 128 + w * 16;           // this wave's 16 q-rows

    // Q fragments (B-operand rows = q); scale pre-folded in k_gemm_qkv
    bf16x8 qa[2];
#pragma unroll
    for (int ki = 0; ki < 2; ki++)
        qa[ki] = *(const bf16x8*)&q[((size_t)bh * 1024 + qr0 + ln) * 64 + ki * 32 + quad * 8];

    const __bf16* kbase = kk + (size_t)bh * 1024 * 64;
    const __bf16* vbase = vt + (size_t)bh * 64 * 1024;

    f32x4 oacc[4] = {};      // O^T: row hd = ni*16+quad*4+r, col q = ln
    f32x4 lacc = {};         // l[q=ln] broadcast in all 4 regs

    bf16x8 ones;
#pragma unroll
    for (int j = 0; j < 8; j++) ones[j] = (__bf16)1.0f;

    for (int st = 0; st < 16; st++) {
        // stage K [64][64] and V^T [64][64]: wave w stages 8 rows of each
        async16(kbase + (size_t)(st * 64 + w * 8 + srow) * 64 + scol, &Ks[w * 8][0]);
        async16(vbase + (size_t)(w * 8 + srow) * 1024 + st * 64 + scol, &Vs[w * 8][0]);
        __syncthreads();

        // S^T = K Q^T (rows = s, cols = q); softmax fused per si
#pragma unroll
        for (int si = 0; si < 4; si++) {
            bf16x8 kb0 = *(const bf16x8*)&Ks[si * 16 + ln][((quad    ) ^ lx) * 8];
            bf16x8 kb1 = *(const bf16x8*)&Ks[si * 16 + ln][((quad + 4) ^ lx) * 8];
            f32x4 sc = {};
            sc = mfma16(kb0, qa[0], sc);
            sc = mfma16(kb1, qa[1], sc);
            // lane holds s = si*16 + quad*4 + r for q = ln:
            // 4 consecutive s -> one packed b64 store into A-layout Ps
            bf16x4 pk;
#pragma unroll
            for (int r = 0; r < 4; r++)
                pk[r] = (__bf16)exp2f(sc[r]);
            *(bf16x4*)((char*)&Ps[w][ln][0]
                       + (((si * 2 + (quad >> 1)) ^ lx) * 16) + (quad & 1) * 8) = pk;
        }

        // O^T += V^T P^T ; l += 1 * P^T   (transposed PV: C rows = hd)
#pragma unroll
        for (int kt = 0; kt < 2; kt++) {
            bf16x8 pa = *(const bf16x8*)&Ps[w][ln][((kt * 4 + quad) ^ lx) * 8];
#pragma unroll
            for (int ni = 0; ni < 4; ni++) {
                bf16x8 vb = *(const bf16x8*)&Vs[ni * 16 + ln][((kt * 4 + quad) ^ lx) * 8];
                oacc[ni] = mfma16(vb, pa, oacc[ni]);
            }
            lacc = mfma16(ones, pa, lacc);
        }
        __syncthreads();
    }

    // epilogue: *inv, rotate with mat_o in-register (pairs are regs r0/r1,
    // r2/r3), packed 8B store to head-major od2[bh][t][hd]
    const float invl = 1.0f / lacc[0];
    const float4* mo4 = (const float4*)mato;
    const int t = qr0 + ln;
#pragma unroll
    for (int ni = 0; ni < 4; ni++) {
        const int hd0 = ni * 16 + quad * 4;
        const int f   = hd0 >> 1;                 // even pair index
        float v0 = oacc[ni][0] * invl;
        float v1 = oacc[ni][1] * invl;
        float v2 = oacc[ni][2] * invl;
        float v3 = oacc[ni][3] * invl;
        float4 m1 = mo4[(size_t)t * 32 + f];
        float4 m2 = mo4[(size_t)t * 32 + f + 1];
        __bf16 pk[4];
        pk[0] = (__bf16)(m1.x * v0 + m1.y * v1);
        pk[1] = (__bf16)(m1.z * v0 + m1.w * v1);
        pk[2] = (__bf16)(m2.x * v2 + m2.y * v3);
        pk[3] = (__bf16)(m2.z * v2 + m2.w * v3);
        *(uint2*)&od[((size_t)bh * 1024 + t) * 64 + hd0] = *(const uint2*)pk;
    }
}

// ---------------------------------------------------------------------------
// 5) out-proj GEMM 16384x512x512 + bias, fp32 output [b][o][t]
//    R(this): same async double-buffer as k_gemm_qkv. A = head-major
//    od2[bh][t][hd] (k-chunk 64 == one head's contiguous row, step
//    +k0*1024); W = wob pre-permuted. 128x128 tile, grid 128x4 = 512
//    blocks = exactly 2/CU.
// ---------------------------------------------------------------------------
__global__ __launch_bounds__(256) void k_gemm_out(
        const __bf16* __restrict__ A, const __bf16* __restrict__ W,
        const float* __restrict__ bias, float* __restrict__ out)
{
    __shared__ __bf16 As[2][128][64];   // 32 KB
    __shared__ __bf16 Bs[2][128][64];   // 32 KB
    const int tid = threadIdx.x;
    const int m0 = blockIdx.x * 128;
    const int n0 = blockIdx.y * 128;
    const int lane = tid & 63, w = tid >> 6;
    const int ln = lane & 15, quad = lane >> 4;
    const int wr = w >> 1, wc = w & 1;

    const int srow = lane >> 3;
    const int scol = (((lane & 7) ^ srow) * 8);

    const int bb = m0 >> 10, t00 = m0 & 1023;        // 128 | 1024 so single b

    const __bf16* arow[4];
    const __bf16* brow[4];
#pragma unroll
    for (int jj = 0; jj < 4; jj++) {
        int rr = w * 32 + jj * 8 + srow;
        arow[jj] = &A[((size_t)bb * 8192 + t00 + rr) * 64 + scol];
        brow[jj] = &W[(size_t)(n0 + rr) * 512 + scol];
    }

    f32x4 acc[4][4] = {};

    // prologue: stage k-tile 0 into buf 0
#pragma unroll
    for (int jj = 0; jj < 4; jj++) {
        async16(arow[jj], &As[0][w * 32 + jj * 8][0]);
        async16(brow[jj], &Bs[0][w * 32 + jj * 8][0]);
    }
    __syncthreads();

#pragma unroll
    for (int it = 0; it < 8; ++it) {
        const int cur = it & 1;
        if (it < 7) {
            const int k1 = (it + 1) * 64;
#pragma unroll
            for (int jj = 0; jj < 4; jj++) {
                async16(arow[jj] + (size_t)k1 * 1024, &As[cur ^ 1][w * 32 + jj * 8][0]);
                async16(brow[jj] + k1,                &Bs[cur ^ 1][w * 32 + jj * 8][0]);
            }
        }
#pragma unroll
        for (int h = 0; h < 2; h++) {
            bf16x8 af[4], wf[4];
#pragma unroll
            for (int mi = 0; mi < 4; mi++)
                af[mi] = *(const bf16x8*)&As[cur][wr * 64 + mi * 16 + ln][(((h * 4 + quad) ^ (ln & 7)) * 8)];
#pragma unroll
            for (int ni = 0; ni < 4; ni++)
                wf[ni] = *(const bf16x8*)&Bs[cur][wc * 64 + ni * 16 + ln][(((h * 4 + quad) ^ (ln & 7)) * 8)];
#pragma unroll
            for (int mi = 0; mi < 4; mi++)
#pragma unroll
                for (int ni = 0; ni < 4; ni++)
                    acc[mi][ni] = mfma16(af[mi], wf[ni], acc[mi][ni]);
        }
        __syncthreads();
    }

    const int rowbase = m0 + wr * 64;
    const int bb2 = rowbase >> 10, t0 = rowbase & 1023;
#pragma unroll
    for (int ni = 0; ni < 4; ni++) {
        int o = n0 + wc * 64 + ni * 16 + ln;
        float bias_o = bias[o];
#pragma unroll
        for (int mi = 0; mi < 4; mi++) {
            int t = t0 + mi * 16 + quad * 4;
            f32x4 v = acc[mi][ni];
            v[0] += bias_o; v[1] += bias_o; v[2] += bias_o; v[3] += bias_o;
            *(f32x4*)&out[((size_t)bb2 * 512 + o) * 1024 + t] = v;
        }
    }
}

// ---------------------------------------------------------------------------
extern "C" void kernel_launch(void* const* d_in, const int* in_sizes, int n_in,
                              void* d_out, int out_size, void* d_ws, size_t ws_size,
                              hipStream_t stream) {
    (void)in_sizes; (void)n_in; (void)out_size; (void)ws_size;
    const float* x     = (const float*)d_in[0];
    const float* w_qkv = (const float*)d_in[1];
    const float* b_qkv = (const float*)d_in[2];
    const float* w_o   = (const float*)d_in[3];
    const float* b_o   = (const float*)d_in[4];
    const float* mat_q = (const float*)d_in[5];
    const float* mat_k = (const float*)d_in[6];
    const float* mat_v = (const float*)d_in[7];
    const float* mat_o = (const float*)d_in[8];
    float* out = (float*)d_out;

    char* p = (char*)d_ws;
    __bf16* wqb = (__bf16*)p;  p += (size_t)3 * 512 * 512 * 2;        // 1.5 MB
    __bf16* wob = (__bf16*)p;  p += (size_t)512 * 512 * 2;            // 0.5 MB (k-permuted)
    char* xt_base = p;
    __bf16* xt  = (__bf16*)p;  p += (size_t)16384 * 512 * 2;          // 16.8 MB
    __bf16* qd  = (__bf16*)p;  p += (size_t)128 * 1024 * 64 * 2;      // 16.8 MB (q pre-scaled)
    __bf16* kd  = (__bf16*)p;  p += (size_t)128 * 1024 * 64 * 2;      // 16.8 MB
    __bf16* vtd = (__bf16*)p;  p += (size_t)128 * 64 * 1024 * 2;      // 16.8 MB
    __bf16* od  = (__bf16*)xt_base;   // head-major od2[bh][t][hd]; aliases dead xt

    k_convert_w  <<<dim3(3072),       dim3(256),    0, stream>>>(w_qkv, w_o, wqb, wob);
    k_transpose_x<<<dim3(16, 8, 16),  dim3(64, 4),  0, stream>>>(x, xt);
    k_gemm_qkv   <<<dim3(128, 12),    dim3(256),    0, stream>>>(xt, wqb, b_qkv, mat_q, mat_k, mat_v, qd, kd, vtd);
    k_attn       <<<dim3(128, 8),     dim3(512),    0, stream>>>(qd, kd, vtd, mat_o, od);
    k_gemm_out   <<<dim3(128, 4),     dim3(256),    0, stream>>>(od, wob, b_o, out);
}

// Round 6
// 223.800 us; speedup vs baseline: 1.0254x; 1.0254x over previous
//
#include <hip/hip_runtime.h>

// ---------------------------------------------------------------------------
// Problem constants
//   B=16, C=512, H=W=32 -> T=1024, HEADS=8, HD=64, pairs F=32
// ---------------------------------------------------------------------------

typedef __bf16 bf16x8 __attribute__((ext_vector_type(8)));
typedef __bf16 bf16x4 __attribute__((ext_vector_type(4)));
typedef float  f32x4  __attribute__((ext_vector_type(4)));

__device__ __forceinline__ f32x4 mfma16(bf16x8 a, bf16x8 b, f32x4 c) {
    return __builtin_amdgcn_mfma_f32_16x16x32_bf16(a, b, c, 0, 0, 0);
}

// async 16B global -> LDS (dest = wave-uniform base + lane*16)
__device__ __forceinline__ void async16(const void* g, void* l) {
    __builtin_amdgcn_global_load_lds(
        (const __attribute__((address_space(1))) void*)g,
        (__attribute__((address_space(3))) void*)l, 16, 0, 0);
}

// ---------------------------------------------------------------------------
// 1) weight conversion fp32 -> bf16.
//    wo k-PERMUTED: wob[o][nh*64+hd] = wo[o][hd*8+nh] (head-major od2).
// ---------------------------------------------------------------------------
__global__ void k_convert_w(const float* __restrict__ wq, const float* __restrict__ wo,
                            __bf16* __restrict__ wqb, __bf16* __restrict__ wob) {
    int i = blockIdx.x * 256 + threadIdx.x;          // grid covers 786432
    if (i < 3 * 512 * 512) wqb[i] = (__bf16)wq[i];
    if (i < 512 * 512) {
        int o = i >> 9, k2 = i & 511;
        int nh = k2 >> 6, hd = k2 & 63;
        wob[i] = (__bf16)wo[o * 512 + hd * 8 + nh];
    }
}

// ---------------------------------------------------------------------------
// 2) x [B][C][T] fp32  ->  xt [B*T][C] bf16   (LDS tile transpose)
// ---------------------------------------------------------------------------
__global__ void k_transpose_x(const float* __restrict__ x, __bf16* __restrict__ xt) {
    __shared__ float tile[64][65];                   // 16.6 KB
    const int b  = blockIdx.z;
    const int c0 = blockIdx.y * 64;
    const int t0 = blockIdx.x * 64;
    const int tx = threadIdx.x, ty = threadIdx.y;    // (64, 4)
    const float* xp = x + ((size_t)b * 512 + c0) * 1024 + t0;
#pragma unroll
    for (int j = 0; j < 16; j++)
        tile[ty + j * 4][tx] = xp[(ty + j * 4) * 1024 + tx];
    __syncthreads();
    __bf16* xo = xt + ((size_t)b * 1024 + t0) * 512 + c0;
#pragma unroll
    for (int j = 0; j < 16; j++)
        xo[(ty + j * 4) * 512 + tx] = (__bf16)tile[tx][ty + j * 4];
}

// ---------------------------------------------------------------------------
// 3) QKV GEMM 16384x1536x512 + fused bias + SO(2) rotation + head split.
//    R(this): counted-vmcnt pipeline (T4). R5's dbuf behind __syncthreads
//    was neutral: syncthreads drains vmcnt(0) (m99/m131 trap). Now: raw
//    s_barrier + s_waitcnt vmcnt(6) (never 0 mid-loop) + lgkmcnt(0)+
//    sched_barrier(0) (rule #18), 2-tile-deep prefetch. Per iter:
//      ds_read frags -> lgkm(0) -> barrier -> stage(t+2 into freed buf)
//      -> setprio(1) 32 MFMA setprio(0) -> vmcnt(6) -> barrier.
//    Also BN 128->256: A re-staged 6x not 12x (A-tiles come from L3; that
//    staged traffic, not HBM, was the R5 wall). 512 thr / 8 waves (2x4),
//    LDS 96 KB dbuf, grid 128x6. Head-grouped cols; q pre-scaled.
// ---------------------------------------------------------------------------
__global__ __launch_bounds__(512) void k_gemm_qkv(
        const __bf16* __restrict__ A, const __bf16* __restrict__ W,
        const float* __restrict__ bias,
        const float* __restrict__ matq, const float* __restrict__ matk,
        const float* __restrict__ matv,
        __bf16* __restrict__ qd, __bf16* __restrict__ kd, __bf16* __restrict__ vtd)
{
    __shared__ __bf16 As[2][128][64];   // 32 KB
    __shared__ __bf16 Bs[2][256][64];   // 64 KB
    const int tid = threadIdx.x;
    const int m0 = blockIdx.x * 128;
    const int jb = blockIdx.y;              // 0..5
    const int part = jb >> 1;               // 0=q 1=k 2=v
    const int nh_base = (jb & 1) * 4;       // heads nh_base + wc
    const int lane = tid & 63, w = tid >> 6;     // 8 waves
    const int ln = lane & 15, quad = lane >> 4;
    const int wr = w >> 2, wc = w & 3;      // 2x4 wave grid, 64x64 each

    const int srow = lane >> 3;                       // 0..7
    const int scol = (((lane & 7) ^ srow) * 8);       // xor chunk swizzle

    // per-wave staging rows: A 16 rows (2 async16), B 32 rows (4 async16)
    const __bf16* arow[2];
    const __bf16* brow[4];
#pragma unroll
    for (int jj = 0; jj < 2; jj++) {
        int rr = w * 16 + jj * 8 + srow;              // 0..127
        arow[jj] = &A[(size_t)(m0 + rr) * 512 + scol];
    }
#pragma unroll
    for (int jj = 0; jj < 4; jj++) {
        int rr = w * 32 + jj * 8 + srow;              // 0..255
        int o = part * 512 + (rr & 63) * 8 + nh_base + (rr >> 6);
        brow[jj] = &W[(size_t)o * 512 + scol];
    }

    f32x4 acc[4][4] = {};

#define STAGE_QKV(T, BUF)                                                   \
    do {                                                                    \
        const int _k0 = (T) * 64;                                           \
        _Pragma("unroll")                                                   \
        for (int jj = 0; jj < 2; jj++)                                      \
            async16(arow[jj] + _k0, &As[BUF][w * 16 + jj * 8][0]);          \
        _Pragma("unroll")                                                   \
        for (int jj = 0; jj < 4; jj++)                                      \
            async16(brow[jj] + _k0, &Bs[BUF][w * 32 + jj * 8][0]);          \
    } while (0)

    // prologue: tiles 0,1 in flight; wait tile0 (my oldest 6), sync
    STAGE_QKV(0, 0);
    STAGE_QKV(1, 1);
    asm volatile("s_waitcnt vmcnt(6)" ::: "memory");
    __builtin_amdgcn_s_barrier();

#pragma unroll
    for (int t = 0; t < 8; ++t) {
        const int cur = t & 1;
        // 1. all fragment reads for this K-tile (16 x ds_read_b128)
        bf16x8 af[2][4], wf[2][4];
#pragma unroll
        for (int h = 0; h < 2; h++) {
#pragma unroll
            for (int mi = 0; mi < 4; mi++)
                af[h][mi] = *(const bf16x8*)&As[cur][wr * 64 + mi * 16 + ln][(((h * 4 + quad) ^ (ln & 7)) * 8)];
#pragma unroll
            for (int ni = 0; ni < 4; ni++)
                wf[h][ni] = *(const bf16x8*)&Bs[cur][wc * 64 + ni * 16 + ln][(((h * 4 + quad) ^ (ln & 7)) * 8)];
        }
        // 2. my reads landed; fence MFMA hoist (rule #18); all waves done reading
        asm volatile("s_waitcnt lgkmcnt(0)" ::: "memory");
        __builtin_amdgcn_sched_barrier(0);
        __builtin_amdgcn_s_barrier();
        // 3. stage t+2 into the buffer tile t just vacated
        if (t < 6) STAGE_QKV(t + 2, cur);
        // 4. MFMA burst
        __builtin_amdgcn_s_setprio(1);
#pragma unroll
        for (int h = 0; h < 2; h++)
#pragma unroll
            for (int mi = 0; mi < 4; mi++)
#pragma unroll
                for (int ni = 0; ni < 4; ni++)
                    acc[mi][ni] = mfma16(af[h][mi], wf[h][ni], acc[mi][ni]);
        __builtin_amdgcn_s_setprio(0);
        // 5. tile t+1 landed (counted: t+2's 6 may stay in flight), sync
        if (t < 6) { asm volatile("s_waitcnt vmcnt(6)" ::: "memory"); }
        else       { asm volatile("s_waitcnt vmcnt(0)" ::: "memory"); }
        __builtin_amdgcn_s_barrier();
    }
#undef STAGE_QKV

    const int nh = nh_base + wc;
    const int rowbase = m0 + wr * 64;
    const int b  = rowbase >> 10, t0 = rowbase & 1023;
    const int bh = b * 8 + nh;
    const int ip = ln & 1;
    const float2* matp = (const float2*)(part == 0 ? matq : (part == 1 ? matk : matv));
    __bf16* qkdst = (part == 0) ? qd : kd;
    // q gets the softmax scale folded in (pre-cast: single rounding)
    const float qscale = (part == 0) ? 0.18033688011112042f : 1.0f;

#pragma unroll
    for (int ni = 0; ni < 4; ni++) {
        const int hd = ni * 16 + ln;
        const int f  = hd >> 1;
        const float bias_o = bias[part * 512 + hd * 8 + nh];
#pragma unroll
        for (int mi = 0; mi < 4; mi++) {
            const int tq = t0 + mi * 16 + quad * 4;   // first of this frag's 4 t's
            if (part < 2) {
#pragma unroll
                for (int r = 0; r < 4; r++) {
                    int t = tq + r;
                    float val = acc[mi][ni][r] + bias_o;
                    float pr  = __shfl_xor(val, 1);
                    float2 mv = matp[((size_t)t * 32 + f) * 2 + ip];
                    float e  = ip ? pr : val;
                    float oo = ip ? val : pr;
                    float rv = (mv.x * e + mv.y * oo) * qscale;
                    qkdst[((size_t)bh * 1024 + t) * 64 + hd] = (__bf16)rv;
                }
            } else {
                __bf16 pack[4];
#pragma unroll
                for (int r = 0; r < 4; r++) {
                    int t = tq + r;
                    float val = acc[mi][ni][r] + bias_o;
                    float pr  = __shfl_xor(val, 1);
                    float2 mv = matp[((size_t)t * 32 + f) * 2 + ip];
                    float e  = ip ? pr : val;
                    float oo = ip ? val : pr;
                    pack[r] = (__bf16)(mv.x * e + mv.y * oo);
                }
                *(uint2*)&vtd[((size_t)bh * 64 + hd) * 1024 + tq] = *(const uint2*)pack;
            }
        }
    }
}

// ---------------------------------------------------------------------------
// 4) Flash attention. R(this): q-tile 128 -> 256 (8 waves x 32 q-rows,
//    the R3 dual-mi shape that passed): K/V staged traffic halves
//    (262 -> 131 MB through L2/L3). LDS 48 KB -> 3 blocks/CU. Swapped
//    QK^T, transposed PV, ones-MFMA l-sums, head-major od2 stores,
//    q pre-scaled. Grid (128 bh, 4 qt).
// ---------------------------------------------------------------------------
__global__ __launch_bounds__(512) void k_attn(
        const __bf16* __restrict__ q, const __bf16* __restrict__ kk,
        const __bf16* __restrict__ vt, const float* __restrict__ mato,
        __bf16* __restrict__ od)
{
    __shared__ __bf16 Ks[64][64];        // [s][d]   8 KB, XOR-chunk layout
    __shared__ __bf16 Vs[64][64];        // [hd][s]  8 KB, XOR-chunk layout
    __shared__ __bf16 Ps[8][32][64];     // per-wave P (rows=q), 32 KB
    const int bh = blockIdx.x, qt = blockIdx.y;
    const int tid = threadIdx.x, w = tid >> 6, lane = tid & 63;
    const int ln = lane & 15, quad = lane >> 4;
    const int lx = ln & 7;                       // xor key for frag reads
    const int srow = lane >> 3;
    const int scol = ((lane & 7) ^ srow) * 8;    // xor chunk source swizzle
    const int qr0 = qt * 256 + w * 32;           // this wave's 32 q-rows

    // Q fragments (B-operand rows = q); scale pre-folded in k_gemm_qkv
    bf16x8 qa[2][2];
#pragma unroll
    for (int mi = 0; mi < 2; mi++)
#pragma unroll
        for (int ki = 0; ki < 2; ki++)
            qa[mi][ki] = *(const bf16x8*)&q[((size_t)bh * 1024 + qr0 + mi * 16 + ln) * 64 + ki * 32 + quad * 8];

    const __bf16* kbase = kk + (size_t)bh * 1024 * 64;
    const __bf16* vbase = vt + (size_t)bh * 64 * 1024;

    f32x4 oacc[2][4] = {};   // O^T: row hd = ni*16+quad*4+r, col q = mi*16+ln
    f32x4 lacc[2] = {};      // l[q] broadcast in all 4 regs

    bf16x8 ones;
#pragma unroll
    for (int j = 0; j < 8; j++) ones[j] = (__bf16)1.0f;

    for (int st = 0; st < 16; st++) {
        // stage K [64][64] and V^T [64][64]: wave w stages 8 rows of each
        async16(kbase + (size_t)(st * 64 + w * 8 + srow) * 64 + scol, &Ks[w * 8][0]);
        async16(vbase + (size_t)(w * 8 + srow) * 1024 + st * 64 + scol, &Vs[w * 8][0]);
        __syncthreads();

        // S^T = K Q^T (rows = s, cols = q); softmax fused per si
#pragma unroll
        for (int si = 0; si < 4; si++) {
            bf16x8 kb0 = *(const bf16x8*)&Ks[si * 16 + ln][((quad    ) ^ lx) * 8];
            bf16x8 kb1 = *(const bf16x8*)&Ks[si * 16 + ln][((quad + 4) ^ lx) * 8];
            f32x4 sc[2] = {};
#pragma unroll
            for (int mi = 0; mi < 2; mi++) {
                sc[mi] = mfma16(kb0, qa[mi][0], sc[mi]);
                sc[mi] = mfma16(kb1, qa[mi][1], sc[mi]);
            }
            // lane holds s = si*16 + quad*4 + r for q = mi*16 + ln:
            // 4 consecutive s -> one packed b64 store into A-layout Ps
#pragma unroll
            for (int mi = 0; mi < 2; mi++) {
                bf16x4 pk;
#pragma unroll
                for (int r = 0; r < 4; r++)
                    pk[r] = (__bf16)exp2f(sc[mi][r]);
                *(bf16x4*)((char*)&Ps[w][mi * 16 + ln][0]
                           + (((si * 2 + (quad >> 1)) ^ lx) * 16) + (quad & 1) * 8) = pk;
            }
        }

        // O^T += V^T P^T ; l += 1 * P^T   (transposed PV: C rows = hd)
#pragma unroll
        for (int kt = 0; kt < 2; kt++) {
            bf16x8 pa[2];
#pragma unroll
            for (int mi = 0; mi < 2; mi++)
                pa[mi] = *(const bf16x8*)&Ps[w][mi * 16 + ln][((kt * 4 + quad) ^ lx) * 8];
#pragma unroll
            for (int ni = 0; ni < 4; ni++) {
                bf16x8 vb = *(const bf16x8*)&Vs[ni * 16 + ln][((kt * 4 + quad) ^ lx) * 8];
                oacc[0][ni] = mfma16(vb, pa[0], oacc[0][ni]);
                oacc[1][ni] = mfma16(vb, pa[1], oacc[1][ni]);
            }
            lacc[0] = mfma16(ones, pa[0], lacc[0]);
            lacc[1] = mfma16(ones, pa[1], lacc[1]);
        }
        __syncthreads();
    }

    // epilogue: *inv, rotate with mat_o in-register (pairs are regs r0/r1,
    // r2/r3), packed 8B store to head-major od2[bh][t][hd]
    const float4* mo4 = (const float4*)mato;
#pragma unroll
    for (int mi = 0; mi < 2; mi++) {
        const int t = qr0 + mi * 16 + ln;
        const float invl = 1.0f / lacc[mi][0];
#pragma unroll
        for (int ni = 0; ni < 4; ni++) {
            const int hd0 = ni * 16 + quad * 4;
            const int f   = hd0 >> 1;                 // even pair index
            float v0 = oacc[mi][ni][0] * invl;
            float v1 = oacc[mi][ni][1] * invl;
            float v2 = oacc[mi][ni][2] * invl;
            float v3 = oacc[mi][ni][3] * invl;
            float4 m1 = mo4[(size_t)t * 32 + f];
            float4 m2 = mo4[(size_t)t * 32 + f + 1];
            __bf16 pk[4];
            pk[0] = (__bf16)(m1.x * v0 + m1.y * v1);
            pk[1] = (__bf16)(m1.z * v0 + m1.w * v1);
            pk[2] = (__bf16)(m2.x * v2 + m2.y * v3);
            pk[3] = (__bf16)(m2.z * v2 + m2.w * v3);
            *(uint2*)&od[((size_t)bh * 1024 + t) * 64 + hd0] = *(const uint2*)pk;
        }
    }
}

// ---------------------------------------------------------------------------
// 5) out-proj GEMM 16384x512x512 + bias, fp32 output [b][o][t]
//    R(this): same counted-vmcnt pipeline as k_gemm_qkv; BN=256 (A staged
//    2x). A = head-major od2 (k-chunk 64 == one head's row, step +k0*1024);
//    W = wob pre-permuted. Grid 128x2 = 256 blocks = 1/CU, 512 thr.
// ---------------------------------------------------------------------------
__global__ __launch_bounds__(512) void k_gemm_out(
        const __bf16* __restrict__ A, const __bf16* __restrict__ W,
        const float* __restrict__ bias, float* __restrict__ out)
{
    __shared__ __bf16 As[2][128][64];   // 32 KB
    __shared__ __bf16 Bs[2][256][64];   // 64 KB
    const int tid = threadIdx.x;
    const int m0 = blockIdx.x * 128;
    const int n0 = blockIdx.y * 256;
    const int lane = tid & 63, w = tid >> 6;
    const int ln = lane & 15, quad = lane >> 4;
    const int wr = w >> 2, wc = w & 3;      // 2x4 wave grid, 64x64 each

    const int srow = lane >> 3;
    const int scol = (((lane & 7) ^ srow) * 8);

    const int bb = m0 >> 10, t00 = m0 & 1023;        // 128 | 1024 so single b

    const __bf16* arow[2];
    const __bf16* brow[4];
#pragma unroll
    for (int jj = 0; jj < 2; jj++) {
        int rr = w * 16 + jj * 8 + srow;
        arow[jj] = &A[((size_t)bb * 8192 + t00 + rr) * 64 + scol];
    }
#pragma unroll
    for (int jj = 0; jj < 4; jj++) {
        int rr = w * 32 + jj * 8 + srow;
        brow[jj] = &W[(size_t)(n0 + rr) * 512 + scol];
    }

    f32x4 acc[4][4] = {};

#define STAGE_OUT(T, BUF)                                                   \
    do {                                                                    \
        const int _k0 = (T) * 64;                                           \
        _Pragma("unroll")                                                   \
        for (int jj = 0; jj < 2; jj++)                                      \
            async16(arow[jj] + (size_t)_k0 * 1024, &As[BUF][w * 16 + jj * 8][0]); \
        _Pragma("unroll")                                                   \
        for (int jj = 0; jj < 4; jj++)                                      \
            async16(brow[jj] + _k0, &Bs[BUF][w * 32 + jj * 8][0]);          \
    } while (0)

    STAGE_OUT(0, 0);
    STAGE_OUT(1, 1);
    asm volatile("s_waitcnt vmcnt(6)" ::: "memory");
    __builtin_amdgcn_s_barrier();

#pragma unroll
    for (int t = 0; t < 8; ++t) {
        const int cur = t & 1;
        bf16x8 af[2][4], wf[2][4];
#pragma unroll
        for (int h = 0; h < 2; h++) {
#pragma unroll
            for (int mi = 0; mi < 4; mi++)
                af[h][mi] = *(const bf16x8*)&As[cur][wr * 64 + mi * 16 + ln][(((h * 4 + quad) ^ (ln & 7)) * 8)];
#pragma unroll
            for (int ni = 0; ni < 4; ni++)
                wf[h][ni] = *(const bf16x8*)&Bs[cur][wc * 64 + ni * 16 + ln][(((h * 4 + quad) ^ (ln & 7)) * 8)];
        }
        asm volatile("s_waitcnt lgkmcnt(0)" ::: "memory");
        __builtin_amdgcn_sched_barrier(0);
        __builtin_amdgcn_s_barrier();
        if (t < 6) STAGE_OUT(t + 2, cur);
        __builtin_amdgcn_s_setprio(1);
#pragma unroll
        for (int h = 0; h < 2; h++)
#pragma unroll
            for (int mi = 0; mi < 4; mi++)
#pragma unroll
                for (int ni = 0; ni < 4; ni++)
                    acc[mi][ni] = mfma16(af[h][mi], wf[h][ni], acc[mi][ni]);
        __builtin_amdgcn_s_setprio(0);
        if (t < 6) { asm volatile("s_waitcnt vmcnt(6)" ::: "memory"); }
        else       { asm volatile("s_waitcnt vmcnt(0)" ::: "memory"); }
        __builtin_amdgcn_s_barrier();
    }
#undef STAGE_OUT

    const int rowbase = m0 + wr * 64;
    const int bb2 = rowbase >> 10, t0 = rowbase & 1023;
#pragma unroll
    for (int ni = 0; ni < 4; ni++) {
        int o = n0 + wc * 64 + ni * 16 + ln;
        float bias_o = bias[o];
#pragma unroll
        for (int mi = 0; mi < 4; mi++) {
            int t = t0 + mi * 16 + quad * 4;
            f32x4 v = acc[mi][ni];
            v[0] += bias_o; v[1] += bias_o; v[2] += bias_o; v[3] += bias_o;
            *(f32x4*)&out[((size_t)bb2 * 512 + o) * 1024 + t] = v;
        }
    }
}

// ---------------------------------------------------------------------------
extern "C" void kernel_launch(void* const* d_in, const int* in_sizes, int n_in,
                              void* d_out, int out_size, void* d_ws, size_t ws_size,
                              hipStream_t stream) {
    (void)in_sizes; (void)n_in; (void)out_size; (void)ws_size;
    const float* x     = (const float*)d_in[0];
    const float* w_qkv = (const float*)d_in[1];
    const float* b_qkv = (const float*)d_in[2];
    const float* w_o   = (const float*)d_in[3];
    const float* b_o   = (const float*)d_in[4];
    const float* mat_q = (const float*)d_in[5];
    const float* mat_k = (const float*)d_in[6];
    const float* mat_v = (const float*)d_in[7];
    const float* mat_o = (const float*)d_in[8];
    float* out = (float*)d_out;

    char* p = (char*)d_ws;
    __bf16* wqb = (__bf16*)p;  p += (size_t)3 * 512 * 512 * 2;        // 1.5 MB
    __bf16* wob = (__bf16*)p;  p += (size_t)512 * 512 * 2;            // 0.5 MB (k-permuted)
    char* xt_base = p;
    __bf16* xt  = (__bf16*)p;  p += (size_t)16384 * 512 * 2;          // 16.8 MB
    __bf16* qd  = (__bf16*)p;  p += (size_t)128 * 1024 * 64 * 2;      // 16.8 MB (q pre-scaled)
    __bf16* kd  = (__bf16*)p;  p += (size_t)128 * 1024 * 64 * 2;      // 16.8 MB
    __bf16* vtd = (__bf16*)p;  p += (size_t)128 * 64 * 1024 * 2;      // 16.8 MB
    __bf16* od  = (__bf16*)xt_base;   // head-major od2[bh][t][hd]; aliases dead xt

    k_convert_w  <<<dim3(3072),       dim3(256),    0, stream>>>(w_qkv, w_o, wqb, wob);
    k_transpose_x<<<dim3(16, 8, 16),  dim3(64, 4),  0, stream>>>(x, xt);
    k_gemm_qkv   <<<dim3(128, 6),     dim3(512),    0, stream>>>(xt, wqb, b_qkv, mat_q, mat_k, mat_v, qd, kd, vtd);
    k_attn       <<<dim3(128, 4),     dim3(512),    0, stream>>>(qd, kd, vtd, mat_o, od);
    k_gemm_out   <<<dim3(128, 2),     dim3(512),    0, stream>>>(od, wob, b_o, out);
}